// Round 11
// baseline (268.619 us; speedup 1.0000x reference)
//
#include <hip/hip_runtime.h>
#include <math.h>

#define HID 128
#define NEXP 8
#define NGRAPH 64
#define EPC 2048       // edges per chunk (hist/binA blocks)
#define MAXB 512       // max coarse buckets (n <= 131072)
#define NXC 8          // XCD classes (blockIdx&7 heuristic)
#define NREP 8         // pool replicas (atomic-contention spreading)

__device__ inline unsigned short f2bf(float f) {
    unsigned u = __float_as_uint(f);
    u += 0x7FFF + ((u >> 16) & 1);          // RNE
    return (unsigned short)(u >> 16);
}
__device__ inline float bf2f(unsigned short u) {
    return __uint_as_float(((unsigned)u) << 16);
}

// ---------------- init: pool/pcnt/bcnt8 zero, C = W2@Wlin, bb2 = b2@Wlin -------
__global__ void k_init0(float* __restrict__ pool, float* __restrict__ pcnt,
                        const float* __restrict__ W2, const float* __restrict__ Wlin,
                        const float* __restrict__ b2, float* __restrict__ C,
                        float* __restrict__ bb2, int* __restrict__ bcnt8) {
    int i = blockIdx.x * 256 + threadIdx.x;
    if (i < MAXB * NXC) bcnt8[i] = 0;
    if (i < NREP * NGRAPH * NEXP) pool[i] = 0.0f;
    if (i < NREP * NGRAPH) pcnt[i] = 0.0f;
    int ci = i - NREP * NGRAPH * NEXP;
    if (ci >= 0 && ci < HID * NEXP) {        // C[k][j] = sum_m W2[k][m]*Wlin[m][j]
        int k = ci >> 3, j = ci & 7;
        float s = 0.0f;
        for (int m = 0; m < HID; m++) s += W2[k * HID + m] * Wlin[m * NEXP + j];
        C[ci] = s;
    }
    int bi = ci - HID * NEXP;
    if (bi >= 0 && bi < NEXP) {              // bb2[j] = sum_m b2[m]*Wlin[m][j]
        float s = 0.0f;
        for (int m = 0; m < HID; m++) s += b2[m] * Wlin[m * NEXP + bi];
        bb2[bi] = s;
    }
}

// ---------------- pass 0: per-(bucket, xcd-class) totals -----------------------
__global__ void k_hist(const int* __restrict__ dst, int* __restrict__ bcnt8,
                       int e, int nbuck) {
    __shared__ int h[MAXB];
    int c = blockIdx.x, t = threadIdx.x;
    int x = c & (NXC - 1);
    for (int b = t; b < nbuck; b += 256) h[b] = 0;
    __syncthreads();
    int start = c * EPC;
    int end = start + EPC < e ? start + EPC : e;
    for (int i = start + t; i < end; i += 256)
        atomicAdd(&h[dst[i] >> 8], 1);
    __syncthreads();
    for (int b = t; b < nbuck; b += 256)
        if (h[b]) atomicAdd(&bcnt8[b * NXC + x], h[b]);
}

// ---------------- scan of 8*nbuck entries + cursor init (1 block, 512 thr) -----
__global__ void k_cscan(const int* __restrict__ bcnt8, int* __restrict__ boff8,
                        int* __restrict__ gcur8, int e, int m /* = 8*nbuck */) {
    __shared__ int s[512];
    int t = threadIdx.x;
    int base = t * 8;
    int v[8];
    int sum = 0;
#pragma unroll
    for (int j = 0; j < 8; j++) {
        v[j] = (base + j < m) ? bcnt8[base + j] : 0;
        sum += v[j];
    }
    s[t] = sum;
    __syncthreads();
    for (int d = 1; d < 512; d <<= 1) {
        int x = (t >= d) ? s[t - d] : 0;
        __syncthreads();
        s[t] += x;
        __syncthreads();
    }
    int run = s[t] - sum;               // exclusive
#pragma unroll
    for (int j = 0; j < 8; j++) {
        if (base + j < m) {
            boff8[base + j] = run;
            gcur8[base + j] = run;
        }
        run += v[j];
    }
    if (t == 0) boff8[m] = e;
}

// ---------------- pass A: dynamic-reservation binning, XCD-class sub-buffers ---
__global__ void k_binA(const int* __restrict__ src, const int* __restrict__ dst,
                       int* __restrict__ gcur8, unsigned* __restrict__ binned,
                       int e, int nbuck) {
    __shared__ int h[MAXB];
    __shared__ int cur[MAXB];
    int c = blockIdx.x, t = threadIdx.x;
    int x = c & (NXC - 1);
    for (int b = t; b < nbuck; b += 256) h[b] = 0;
    __syncthreads();
    int start = c * EPC;
    int end = start + EPC < e ? start + EPC : e;
    for (int i = start + t; i < end; i += 256)
        atomicAdd(&h[dst[i] >> 8], 1);
    __syncthreads();
    for (int b = t; b < nbuck; b += 256)
        cur[b] = h[b] ? atomicAdd(&gcur8[b * NXC + x], h[b]) : 0;
    __syncthreads();
    for (int i = start + t; i < end; i += 256) {
        int d = dst[i];
        int p = atomicAdd(&cur[d >> 8], 1);
        binned[p] = ((unsigned)(d & 255) << 24) | (unsigned)src[i];
    }
}

// ---------------- pass B: per-bucket fine sort + cnt/off/dinv + xs -------------
__global__ void k_binB(const unsigned* __restrict__ binned, const int* __restrict__ boff8,
                       const float* __restrict__ an, const float* __restrict__ pos,
                       int* __restrict__ cnt, int* __restrict__ off,
                       float* __restrict__ dinv, float4* __restrict__ xs,
                       int* __restrict__ eidx, int n) {
    __shared__ int h[256];
    __shared__ int sc[256];
    __shared__ int cur[256];
    int b = blockIdx.x, t = threadIdx.x;
    int s0 = boff8[b * NXC], s1 = boff8[(b + 1) * NXC];
    h[t] = 0;
    __syncthreads();
    for (int k = s0 + t; k < s1; k += 256)
        atomicAdd(&h[binned[k] >> 24], 1);
    __syncthreads();
    int v = h[t];
    sc[t] = v;
    __syncthreads();
    for (int d = 1; d < 256; d <<= 1) {
        int x = (t >= d) ? sc[t - d] : 0;
        __syncthreads();
        sc[t] += x;
        __syncthreads();
    }
    int ex = sc[t] - v;          // exclusive within bucket
    cur[t] = ex;
    int node = (b << 8) + t;
    if (node < n) {
        float di = rsqrtf((float)v + 1.0f);   // +1 = self-loop
        cnt[node]  = v;
        off[node]  = s0 + ex;
        dinv[node] = di;
        xs[node] = make_float4(an[node] * di, pos[3 * node] * di,
                               pos[3 * node + 1] * di, pos[3 * node + 2] * di);
    }
    __syncthreads();
    for (int k = s0 + t; k < s1; k += 256) {
        unsigned u = binned[k];
        int p = atomicAdd(&cur[u >> 24], 1);
        eidx[s0 + p] = (int)(u & 0xFFFFFF);
    }
}

// ---------------- layer-1 gather, 4 lanes per node -----------------------------
__global__ void k_gx(const float4* __restrict__ xs, const int* __restrict__ eidx,
                     const int* __restrict__ off, const int* __restrict__ cnt,
                     float4* __restrict__ agg4, int n) {
    int t = threadIdx.x;
    int i = blockIdx.x * 64 + (t >> 2);
    if (i >= n) return;
    int sub = t & 3;
    int o = off[i], c = cnt[i];
    float4 a = make_float4(0.0f, 0.0f, 0.0f, 0.0f);
    if (sub == 0) a = xs[i];                   // self-loop
    int k = sub;
    for (; k + 4 < c; k += 8) {
        int i0 = eidx[o + k], i1 = eidx[o + k + 4];
        float4 v0 = xs[i0], v1 = xs[i1];
        a.x += v0.x + v1.x; a.y += v0.y + v1.y;
        a.z += v0.z + v1.z; a.w += v0.w + v1.w;
    }
    if (k < c) {
        float4 v0 = xs[eidx[o + k]];
        a.x += v0.x; a.y += v0.y; a.z += v0.z; a.w += v0.w;
    }
    // quad reduction
    a.x += __shfl_xor(a.x, 1, 64); a.y += __shfl_xor(a.y, 1, 64);
    a.z += __shfl_xor(a.z, 1, 64); a.w += __shfl_xor(a.w, 1, 64);
    a.x += __shfl_xor(a.x, 2, 64); a.y += __shfl_xor(a.y, 2, 64);
    a.z += __shfl_xor(a.z, 2, 64); a.w += __shfl_xor(a.w, 2, 64);
    if (sub == 0) agg4[i] = a;
}

// ---------------- fused layer-1 dense + z projection ---------------------------
__global__ void k_hz(const float4* __restrict__ agg4, const float* __restrict__ W1,
                     const float* __restrict__ b1, const float* __restrict__ C,
                     const float* __restrict__ dinv, unsigned short* __restrict__ z,
                     int n) {
    __shared__ float xh[4][HID];
    int w = threadIdx.x >> 6;
    int i = blockIdx.x * 4 + w;
    int p = threadIdx.x & 63;
    int ic = i < n ? i : n - 1;
    const float2* W1v = (const float2*)W1;
    float2 w0 = W1v[0 * 64 + p], w1 = W1v[1 * 64 + p],
           w2 = W1v[2 * 64 + p], w3 = W1v[3 * 64 + p];
    float4 a = agg4[ic];
    float di = dinv[ic];
    float2 bb = ((const float2*)b1)[p];
    float h0 = fmaxf(di * (a.x * w0.x + a.y * w1.x + a.z * w2.x + a.w * w3.x) + bb.x, 0.0f);
    float h1 = fmaxf(di * (a.x * w0.y + a.y * w1.y + a.z * w2.y + a.w * w3.y) + bb.y, 0.0f);
    xh[w][2 * p]     = h0;
    xh[w][2 * p + 1] = h1;
    __syncthreads();
    int seg = p >> 3, j = p & 7;
    float val = 0.0f;
#pragma unroll
    for (int q = 0; q < 16; q++) {
        int c = seg * 16 + q;
        val += xh[w][c] * C[c * NEXP + j];
    }
#pragma unroll
    for (int m = 8; m < 64; m <<= 1)
        val += __shfl_xor(val, m, 64);
    if (p < 8 && i < n) z[(size_t)i * NEXP + p] = f2bf(val * di);
}

// ---------------- fused gather2 + pooling: 16 lanes/slot (2 halves x 8 comps) --
__global__ void k_gz(const unsigned short* __restrict__ z, const int* __restrict__ eidx,
                     const int* __restrict__ off, const int* __restrict__ cnt,
                     const float* __restrict__ dinv, const int* __restrict__ batch,
                     float* __restrict__ pool, float* __restrict__ pcnt, int n) {
    int t = threadIdx.x;
    int slot = t >> 4;          // 0..15 within block
    int e2 = (t >> 3) & 1;      // edge-parity half
    int j = t & 7;              // component
    int i0 = blockIdx.x * 64 + slot * 4;
    if (i0 >= n) return;
    int i1 = i0 + 4 < n ? i0 + 4 : n;
    int rep = (blockIdx.x + slot) & (NREP - 1);
    float* rp  = pool + (size_t)rep * NGRAPH * NEXP;
    float* rpc = pcnt + (size_t)rep * NGRAPH;

    int curg = -1;
    float r = 0.0f, runlen = 0.0f;
    for (int i = i0; i < i1; i++) {
        float acc = e2 ? 0.0f : bf2f(z[(size_t)i * NEXP + j]);   // self-loop once
        int o = off[i], c = cnt[i];
        int k = e2;
        for (; k + 6 < c; k += 8) {
            int s0 = eidx[o + k],     s1 = eidx[o + k + 2];
            int s2 = eidx[o + k + 4], s3 = eidx[o + k + 6];
            acc += bf2f(z[(size_t)s0 * NEXP + j]) + bf2f(z[(size_t)s1 * NEXP + j]) +
                   bf2f(z[(size_t)s2 * NEXP + j]) + bf2f(z[(size_t)s3 * NEXP + j]);
        }
        for (; k < c; k += 2)
            acc += bf2f(z[(size_t)eidx[o + k] * NEXP + j]);
        float v = dinv[i] * acc;
        int g = batch[i];
        if (g != curg) {                     // slot-uniform branch
            if (curg >= 0) {
                atomicAdd(&rp[curg * NEXP + j], r);
                if ((t & 15) == 0) atomicAdd(&rpc[curg], runlen);
            }
            curg = g; r = v; runlen = 1.0f;
        } else { r += v; runlen += 1.0f; }
    }
    if (curg >= 0) {
        atomicAdd(&rp[curg * NEXP + j], r);
        if ((t & 15) == 0) atomicAdd(&rpc[curg], runlen);
    }
}

// ---------------- replica-sum + mean + (blin + b2@Wlin) + log_softmax ----------
__global__ void k_lsm(const float* __restrict__ pool, const float* __restrict__ pcnt,
                      const float* __restrict__ blin, const float* __restrict__ bb2,
                      float* __restrict__ out) {
    int g = threadIdx.x;
    if (g >= NGRAPH) return;
    float p[NEXP];
#pragma unroll
    for (int k = 0; k < NEXP; k++) p[k] = 0.0f;
    float cg = 0.0f;
#pragma unroll
    for (int rr = 0; rr < NREP; rr++) {
#pragma unroll
        for (int k = 0; k < NEXP; k++) p[k] += pool[rr * NGRAPH * NEXP + g * NEXP + k];
        cg += pcnt[rr * NGRAPH + g];
    }
    float inv = 1.0f / fmaxf(cg, 1.0f);
    float v[NEXP], m = -1e30f;
#pragma unroll
    for (int k = 0; k < NEXP; k++) {
        v[k] = p[k] * inv + blin[k] + bb2[k];
        m = fmaxf(m, v[k]);
    }
    float s = 0.0f;
#pragma unroll
    for (int k = 0; k < NEXP; k++) s += expf(v[k] - m);
    float ls = logf(s);
#pragma unroll
    for (int k = 0; k < NEXP; k++) out[g * NEXP + k] = v[k] - m - ls;
}

extern "C" void kernel_launch(void* const* d_in, const int* in_sizes, int n_in,
                              void* d_out, int out_size, void* d_ws, size_t ws_size,
                              hipStream_t stream) {
    const float* an   = (const float*)d_in[0];
    const float* pos  = (const float*)d_in[1];
    const int*   ei   = (const int*)d_in[2];     // [2, E] flat (int32 view)
    const int*   batch= (const int*)d_in[3];
    const float* W1   = (const float*)d_in[4];
    const float* b1   = (const float*)d_in[5];
    const float* W2   = (const float*)d_in[6];
    const float* b2   = (const float*)d_in[7];
    const float* Wlin = (const float*)d_in[8];
    const float* blin = (const float*)d_in[9];
    float* out = (float*)d_out;

    const int n = in_sizes[0];
    const int e = in_sizes[2] / 2;
    const int* src = ei;
    const int* dst = ei + e;

    const int nbuck = (n + 255) >> 8;            // coarse buckets (<= MAXB)
    const int ch    = (e + EPC - 1) / EPC;       // chunks

    // workspace layout (16B-aligned buffers first)
    char* p = (char*)d_ws;
    float4* xs    = (float4*)p;       p += sizeof(float4) * (size_t)n;
    float4* agg4  = (float4*)p;       p += sizeof(float4) * (size_t)n;
    unsigned short* z = (unsigned short*)p;  p += sizeof(short) * (size_t)n * NEXP;
    float* C      = (float*)p;        p += sizeof(float) * HID * NEXP;
    float* bb2    = (float*)p;        p += sizeof(float) * NEXP;
    float* dinv   = (float*)p;        p += sizeof(float) * (size_t)n;
    float* pool   = (float*)p;        p += sizeof(float) * NREP * NGRAPH * NEXP;
    float* pcnt   = (float*)p;        p += sizeof(float) * NREP * NGRAPH;
    int*   cnt    = (int*)p;          p += sizeof(int) * (size_t)n;
    int*   off    = (int*)p;          p += sizeof(int) * (size_t)n;
    int*   bcnt8  = (int*)p;          p += sizeof(int) * (MAXB * NXC + 8);
    int*   boff8  = (int*)p;          p += sizeof(int) * (MAXB * NXC + 8);
    int*   gcur8  = (int*)p;          p += sizeof(int) * (MAXB * NXC + 8);
    unsigned* binned = (unsigned*)p;  p += sizeof(unsigned) * (size_t)e;
    int*   eidx   = (int*)p;          p += sizeof(int) * (size_t)e;

    // init + CSR build via dynamic-reservation counting sort (XCD-class binning)
    const int initN = NREP * NGRAPH * NEXP + HID * NEXP + NEXP;
    const int initG = initN > MAXB * NXC ? initN : MAXB * NXC;
    k_init0<<<(initG + 255) / 256, 256, 0, stream>>>(pool, pcnt, W2, Wlin, b2, C, bb2, bcnt8);
    k_hist<<<ch, 256, 0, stream>>>(dst, bcnt8, e, nbuck);
    k_cscan<<<1, 512, 0, stream>>>(bcnt8, boff8, gcur8, e, NXC * nbuck);
    k_binA<<<ch, 256, 0, stream>>>(src, dst, gcur8, binned, e, nbuck);
    k_binB<<<nbuck, 256, 0, stream>>>(binned, boff8, an, pos, cnt, off, dinv, xs, eidx, n);

    // layer 1 gather (4-dim, 4 lanes/node) + fused dense/projection to z (8-dim)
    k_gx<<<(n + 63) / 64, 256, 0, stream>>>(xs, eidx, off, cnt, agg4, n);
    k_hz<<<(n + 3) / 4, 256, 0, stream>>>(agg4, W1, b1, C, dinv, z, n);

    // layer 2 gather in 8-dim z-space + pooling, then log_softmax
    k_gz<<<(n + 63) / 64, 256, 0, stream>>>(z, eidx, off, cnt, dinv, batch, pool, pcnt, n);
    k_lsm<<<1, 64, 0, stream>>>(pool, pcnt, blin, bb2, out);
}

// Round 12
// 266.459 us; speedup vs baseline: 1.0081x; 1.0081x over previous
//
#include <hip/hip_runtime.h>
#include <math.h>

#define HID 128
#define NEXP 8
#define NGRAPH 64
#define EPC 2048       // edges per chunk (hist/binA blocks)
#define MAXB 512       // max coarse buckets (n <= 131072)
#define NXC 8          // XCD classes (blockIdx&7 heuristic)
#define NREP 8         // pool replicas (atomic-contention spreading)
#define NPS 4          // nodes per slot in k_gz

__device__ inline unsigned short f2bf(float f) {
    unsigned u = __float_as_uint(f);
    u += 0x7FFF + ((u >> 16) & 1);          // RNE
    return (unsigned short)(u >> 16);
}
__device__ inline float bf2f(unsigned short u) {
    return __uint_as_float(((unsigned)u) << 16);
}

// ---------------- init: pool/pcnt/bcnt8 zero, C = W2@Wlin, bb2 = b2@Wlin -------
__global__ void k_init0(float* __restrict__ pool, float* __restrict__ pcnt,
                        const float* __restrict__ W2, const float* __restrict__ Wlin,
                        const float* __restrict__ b2, float* __restrict__ C,
                        float* __restrict__ bb2, int* __restrict__ bcnt8) {
    int i = blockIdx.x * 256 + threadIdx.x;
    if (i < MAXB * NXC) bcnt8[i] = 0;
    if (i < NREP * NGRAPH * NEXP) pool[i] = 0.0f;
    if (i < NREP * NGRAPH) pcnt[i] = 0.0f;
    int ci = i - NREP * NGRAPH * NEXP;
    if (ci >= 0 && ci < HID * NEXP) {        // C[k][j] = sum_m W2[k][m]*Wlin[m][j]
        int k = ci >> 3, j = ci & 7;
        float s = 0.0f;
        for (int m = 0; m < HID; m++) s += W2[k * HID + m] * Wlin[m * NEXP + j];
        C[ci] = s;
    }
    int bi = ci - HID * NEXP;
    if (bi >= 0 && bi < NEXP) {              // bb2[j] = sum_m b2[m]*Wlin[m][j]
        float s = 0.0f;
        for (int m = 0; m < HID; m++) s += b2[m] * Wlin[m * NEXP + bi];
        bb2[bi] = s;
    }
}

// ---------------- pass 0: per-(bucket, xcd-class) totals -----------------------
__global__ void k_hist(const int* __restrict__ dst, int* __restrict__ bcnt8,
                       int e, int nbuck) {
    __shared__ int h[MAXB];
    int c = blockIdx.x, t = threadIdx.x;
    int x = c & (NXC - 1);
    for (int b = t; b < nbuck; b += 256) h[b] = 0;
    __syncthreads();
    int start = c * EPC;
    int end = start + EPC < e ? start + EPC : e;
    for (int i = start + t; i < end; i += 256)
        atomicAdd(&h[dst[i] >> 8], 1);
    __syncthreads();
    for (int b = t; b < nbuck; b += 256)
        if (h[b]) atomicAdd(&bcnt8[b * NXC + x], h[b]);
}

// ---------------- scan of 8*nbuck entries + cursor init (1 block, 512 thr) -----
__global__ void k_cscan(const int* __restrict__ bcnt8, int* __restrict__ boff8,
                        int* __restrict__ gcur8, int e, int m /* = 8*nbuck */) {
    __shared__ int s[512];
    int t = threadIdx.x;
    int base = t * 8;
    int v[8];
    int sum = 0;
#pragma unroll
    for (int j = 0; j < 8; j++) {
        v[j] = (base + j < m) ? bcnt8[base + j] : 0;
        sum += v[j];
    }
    s[t] = sum;
    __syncthreads();
    for (int d = 1; d < 512; d <<= 1) {
        int x = (t >= d) ? s[t - d] : 0;
        __syncthreads();
        s[t] += x;
        __syncthreads();
    }
    int run = s[t] - sum;               // exclusive
#pragma unroll
    for (int j = 0; j < 8; j++) {
        if (base + j < m) {
            boff8[base + j] = run;
            gcur8[base + j] = run;
        }
        run += v[j];
    }
    if (t == 0) boff8[m] = e;
}

// ---------------- pass A: LDS counting-sort binning, coalesced run writes ------
__global__ void __launch_bounds__(256) k_binA(
        const int* __restrict__ src, const int* __restrict__ dst,
        int* __restrict__ gcur8, unsigned* __restrict__ binned, int e, int nbuck) {
    __shared__ int h[MAXB];
    __shared__ int ssum[256];
    __shared__ int lstart[MAXB];
    __shared__ int lcur[MAXB];
    __shared__ int gbase[MAXB];
    __shared__ unsigned packed[EPC];
    __shared__ unsigned short sbkt[EPC];
    int c = blockIdx.x, t = threadIdx.x;
    int x = c & (NXC - 1);
    int start = c * EPC;
    int m = e - start < EPC ? e - start : EPC;

    int d[8], sv[8];
#pragma unroll
    for (int j = 0; j < 8; j++) {
        int idx = j * 256 + t;
        if (idx < m) { d[j] = dst[start + idx]; sv[j] = src[start + idx]; }
    }
    h[t] = 0; h[t + 256] = 0;
    __syncthreads();
#pragma unroll
    for (int j = 0; j < 8; j++)
        if (j * 256 + t < m) atomicAdd(&h[d[j] >> 8], 1);
    __syncthreads();
    // exclusive scan of 512 counters (2 per thread)
    int v0 = h[2 * t], v1 = h[2 * t + 1];
    int sum = v0 + v1;
    ssum[t] = sum;
    __syncthreads();
    for (int dd = 1; dd < 256; dd <<= 1) {
        int xx = (t >= dd) ? ssum[t - dd] : 0;
        __syncthreads();
        ssum[t] += xx;
        __syncthreads();
    }
    int ex = ssum[t] - sum;
    lstart[2 * t] = ex;     lstart[2 * t + 1] = ex + v0;
    lcur[2 * t]   = ex;     lcur[2 * t + 1]   = ex + v0;
    __syncthreads();
    // global range reservation per touched bucket
    for (int b = t; b < nbuck; b += 256)
        gbase[b] = h[b] ? atomicAdd(&gcur8[b * NXC + x], h[b]) : 0;
    // LDS sort (scatter to dense local ranks)
#pragma unroll
    for (int j = 0; j < 8; j++) {
        if (j * 256 + t < m) {
            int b = d[j] >> 8;
            int p = atomicAdd(&lcur[b], 1);
            packed[p] = ((unsigned)(d[j] & 255) << 24) | (unsigned)sv[j];
            sbkt[p] = (unsigned short)b;
        }
    }
    __syncthreads();
    // coalesced write-out: consecutive local ranks -> consecutive global slots
    for (int idx = t; idx < m; idx += 256) {
        int b = sbkt[idx];
        binned[gbase[b] + (idx - lstart[b])] = packed[idx];
    }
}

// ---------------- pass B: per-bucket fine sort + cnt/off/dinv + xs -------------
__global__ void k_binB(const unsigned* __restrict__ binned, const int* __restrict__ boff8,
                       const float* __restrict__ an, const float* __restrict__ pos,
                       int* __restrict__ cnt, int* __restrict__ off,
                       float* __restrict__ dinv, float4* __restrict__ xs,
                       int* __restrict__ eidx, int n) {
    __shared__ int h[256];
    __shared__ int sc[256];
    __shared__ int cur[256];
    int b = blockIdx.x, t = threadIdx.x;
    int s0 = boff8[b * NXC], s1 = boff8[(b + 1) * NXC];
    h[t] = 0;
    __syncthreads();
    for (int k = s0 + t; k < s1; k += 256)
        atomicAdd(&h[binned[k] >> 24], 1);
    __syncthreads();
    int v = h[t];
    sc[t] = v;
    __syncthreads();
    for (int d = 1; d < 256; d <<= 1) {
        int x = (t >= d) ? sc[t - d] : 0;
        __syncthreads();
        sc[t] += x;
        __syncthreads();
    }
    int ex = sc[t] - v;          // exclusive within bucket
    cur[t] = ex;
    int node = (b << 8) + t;
    if (node < n) {
        float di = rsqrtf((float)v + 1.0f);   // +1 = self-loop
        cnt[node]  = v;
        off[node]  = s0 + ex;
        dinv[node] = di;
        xs[node] = make_float4(an[node] * di, pos[3 * node] * di,
                               pos[3 * node + 1] * di, pos[3 * node + 2] * di);
    }
    __syncthreads();
    for (int k = s0 + t; k < s1; k += 256) {
        unsigned u = binned[k];
        int p = atomicAdd(&cur[u >> 24], 1);
        eidx[s0 + p] = (int)(u & 0xFFFFFF);
    }
}

// ---------------- layer-1 gather in 4-dim space: agg4 = xs[i] + sum xs[src] ----
__global__ void k_gx(const float4* __restrict__ xs, const int* __restrict__ eidx,
                     const int* __restrict__ off, const int* __restrict__ cnt,
                     float4* __restrict__ agg4, int n) {
    int i = blockIdx.x * 256 + threadIdx.x;
    if (i >= n) return;
    float4 a = xs[i];                       // self-loop
    int o = off[i], c = cnt[i];
    int k = 0;
    for (; k + 8 <= c; k += 8) {
        int id[8];
#pragma unroll
        for (int j = 0; j < 8; j++) id[j] = eidx[o + k + j];
        float4 vv[8];
#pragma unroll
        for (int j = 0; j < 8; j++) vv[j] = xs[id[j]];
#pragma unroll
        for (int j = 0; j < 8; j++) {
            a.x += vv[j].x; a.y += vv[j].y; a.z += vv[j].z; a.w += vv[j].w;
        }
    }
    for (; k < c; k++) {
        float4 vv = xs[eidx[o + k]];
        a.x += vv.x; a.y += vv.y; a.z += vv.z; a.w += vv.w;
    }
    agg4[i] = a;
}

// ---------------- fused layer-1 dense + z projection ---------------------------
__global__ void k_hz(const float4* __restrict__ agg4, const float* __restrict__ W1,
                     const float* __restrict__ b1, const float* __restrict__ C,
                     const float* __restrict__ dinv, unsigned short* __restrict__ z,
                     int n) {
    __shared__ float xh[4][HID];
    int w = threadIdx.x >> 6;
    int i = blockIdx.x * 4 + w;
    int p = threadIdx.x & 63;
    int ic = i < n ? i : n - 1;
    const float2* W1v = (const float2*)W1;
    float2 w0 = W1v[0 * 64 + p], w1 = W1v[1 * 64 + p],
           w2 = W1v[2 * 64 + p], w3 = W1v[3 * 64 + p];
    float4 a = agg4[ic];
    float di = dinv[ic];
    float2 bb = ((const float2*)b1)[p];
    float h0 = fmaxf(di * (a.x * w0.x + a.y * w1.x + a.z * w2.x + a.w * w3.x) + bb.x, 0.0f);
    float h1 = fmaxf(di * (a.x * w0.y + a.y * w1.y + a.z * w2.y + a.w * w3.y) + bb.y, 0.0f);
    xh[w][2 * p]     = h0;
    xh[w][2 * p + 1] = h1;
    __syncthreads();
    int seg = p >> 3, j = p & 7;
    float val = 0.0f;
#pragma unroll
    for (int q = 0; q < 16; q++) {
        int c = seg * 16 + q;
        val += xh[w][c] * C[c * NEXP + j];
    }
#pragma unroll
    for (int m = 8; m < 64; m <<= 1)
        val += __shfl_xor(val, m, 64);
    if (p < 8 && i < n) z[(size_t)i * NEXP + p] = f2bf(val * di);
}

// ---------------- fused gather2 (8-dim bf16 z) + segment pooling ---------------
__global__ void k_gz(const unsigned short* __restrict__ z, const int* __restrict__ eidx,
                     const int* __restrict__ off, const int* __restrict__ cnt,
                     const float* __restrict__ dinv, const int* __restrict__ batch,
                     float* __restrict__ pool, float* __restrict__ pcnt, int n) {
    int t = threadIdx.x;
    int slot = t >> 3;          // 0..31 within block
    int j = t & 7;
    int i0 = blockIdx.x * (32 * NPS) + slot * NPS;
    if (i0 >= n) return;
    int i1 = i0 + NPS < n ? i0 + NPS : n;
    int rep = (blockIdx.x + slot) & (NREP - 1);
    float* rp  = pool + (size_t)rep * NGRAPH * NEXP;
    float* rpc = pcnt + (size_t)rep * NGRAPH;

    int curg = -1;
    float r = 0.0f, runlen = 0.0f;
    for (int i = i0; i < i1; i++) {
        float acc = bf2f(z[(size_t)i * NEXP + j]);   // self-loop
        int o = off[i], c = cnt[i];
        int k = 0;
        for (; k + 4 <= c; k += 4) {
            int s0 = eidx[o + k], s1 = eidx[o + k + 1];
            int s2 = eidx[o + k + 2], s3 = eidx[o + k + 3];
            unsigned short u0 = z[(size_t)s0 * NEXP + j];
            unsigned short u1 = z[(size_t)s1 * NEXP + j];
            unsigned short u2 = z[(size_t)s2 * NEXP + j];
            unsigned short u3 = z[(size_t)s3 * NEXP + j];
            acc += bf2f(u0) + bf2f(u1) + bf2f(u2) + bf2f(u3);
        }
        for (; k < c; k++)
            acc += bf2f(z[(size_t)eidx[o + k] * NEXP + j]);
        float v = dinv[i] * acc;
        int g = batch[i];
        if (g != curg) {                     // slot-uniform branch
            if (curg >= 0) {
                atomicAdd(&rp[curg * NEXP + j], r);
                if (j == 0) atomicAdd(&rpc[curg], runlen);
            }
            curg = g; r = v; runlen = 1.0f;
        } else { r += v; runlen += 1.0f; }
    }
    if (curg >= 0) {
        atomicAdd(&rp[curg * NEXP + j], r);
        if (j == 0) atomicAdd(&rpc[curg], runlen);
    }
}

// ---------------- replica-sum + mean + (blin + b2@Wlin) + log_softmax ----------
__global__ void k_lsm(const float* __restrict__ pool, const float* __restrict__ pcnt,
                      const float* __restrict__ blin, const float* __restrict__ bb2,
                      float* __restrict__ out) {
    int g = threadIdx.x;
    if (g >= NGRAPH) return;
    float p[NEXP];
#pragma unroll
    for (int k = 0; k < NEXP; k++) p[k] = 0.0f;
    float cg = 0.0f;
#pragma unroll
    for (int rr = 0; rr < NREP; rr++) {
#pragma unroll
        for (int k = 0; k < NEXP; k++) p[k] += pool[rr * NGRAPH * NEXP + g * NEXP + k];
        cg += pcnt[rr * NGRAPH + g];
    }
    float inv = 1.0f / fmaxf(cg, 1.0f);
    float v[NEXP], m = -1e30f;
#pragma unroll
    for (int k = 0; k < NEXP; k++) {
        v[k] = p[k] * inv + blin[k] + bb2[k];
        m = fmaxf(m, v[k]);
    }
    float s = 0.0f;
#pragma unroll
    for (int k = 0; k < NEXP; k++) s += expf(v[k] - m);
    float ls = logf(s);
#pragma unroll
    for (int k = 0; k < NEXP; k++) out[g * NEXP + k] = v[k] - m - ls;
}

extern "C" void kernel_launch(void* const* d_in, const int* in_sizes, int n_in,
                              void* d_out, int out_size, void* d_ws, size_t ws_size,
                              hipStream_t stream) {
    const float* an   = (const float*)d_in[0];
    const float* pos  = (const float*)d_in[1];
    const int*   ei   = (const int*)d_in[2];     // [2, E] flat (int32 view)
    const int*   batch= (const int*)d_in[3];
    const float* W1   = (const float*)d_in[4];
    const float* b1   = (const float*)d_in[5];
    const float* W2   = (const float*)d_in[6];
    const float* b2   = (const float*)d_in[7];
    const float* Wlin = (const float*)d_in[8];
    const float* blin = (const float*)d_in[9];
    float* out = (float*)d_out;

    const int n = in_sizes[0];
    const int e = in_sizes[2] / 2;
    const int* src = ei;
    const int* dst = ei + e;

    const int nbuck = (n + 255) >> 8;            // coarse buckets (<= MAXB)
    const int ch    = (e + EPC - 1) / EPC;       // chunks

    // workspace layout (16B-aligned buffers first)
    char* p = (char*)d_ws;
    float4* xs    = (float4*)p;       p += sizeof(float4) * (size_t)n;
    float4* agg4  = (float4*)p;       p += sizeof(float4) * (size_t)n;
    unsigned short* z = (unsigned short*)p;  p += sizeof(short) * (size_t)n * NEXP;
    float* C      = (float*)p;        p += sizeof(float) * HID * NEXP;
    float* bb2    = (float*)p;        p += sizeof(float) * NEXP;
    float* dinv   = (float*)p;        p += sizeof(float) * (size_t)n;
    float* pool   = (float*)p;        p += sizeof(float) * NREP * NGRAPH * NEXP;
    float* pcnt   = (float*)p;        p += sizeof(float) * NREP * NGRAPH;
    int*   cnt    = (int*)p;          p += sizeof(int) * (size_t)n;
    int*   off    = (int*)p;          p += sizeof(int) * (size_t)n;
    int*   bcnt8  = (int*)p;          p += sizeof(int) * (MAXB * NXC + 8);
    int*   boff8  = (int*)p;          p += sizeof(int) * (MAXB * NXC + 8);
    int*   gcur8  = (int*)p;          p += sizeof(int) * (MAXB * NXC + 8);
    unsigned* binned = (unsigned*)p;  p += sizeof(unsigned) * (size_t)e;
    int*   eidx   = (int*)p;          p += sizeof(int) * (size_t)e;

    // init + CSR build via dynamic-reservation counting sort (LDS-sorted writes)
    const int initN = NREP * NGRAPH * NEXP + HID * NEXP + NEXP;
    const int initG = initN > MAXB * NXC ? initN : MAXB * NXC;
    k_init0<<<(initG + 255) / 256, 256, 0, stream>>>(pool, pcnt, W2, Wlin, b2, C, bb2, bcnt8);
    k_hist<<<ch, 256, 0, stream>>>(dst, bcnt8, e, nbuck);
    k_cscan<<<1, 512, 0, stream>>>(bcnt8, boff8, gcur8, e, NXC * nbuck);
    k_binA<<<ch, 256, 0, stream>>>(src, dst, gcur8, binned, e, nbuck);
    k_binB<<<nbuck, 256, 0, stream>>>(binned, boff8, an, pos, cnt, off, dinv, xs, eidx, n);

    // layer 1 gather (4-dim) + fused dense/projection to z (8-dim)
    k_gx<<<(n + 255) / 256, 256, 0, stream>>>(xs, eidx, off, cnt, agg4, n);
    k_hz<<<(n + 3) / 4, 256, 0, stream>>>(agg4, W1, b1, C, dinv, z, n);

    // layer 2 gather in 8-dim z-space + pooling, then log_softmax
    k_gz<<<(n + 32 * NPS - 1) / (32 * NPS), 256, 0, stream>>>(z, eidx, off, cnt,
                                                              dinv, batch, pool, pcnt, n);
    k_lsm<<<1, 64, 0, stream>>>(pool, pcnt, blin, bb2, out);
}

// Round 13
// 234.680 us; speedup vs baseline: 1.1446x; 1.1354x over previous
//
#include <hip/hip_runtime.h>
#include <math.h>

#define HID 128
#define NEXP 8
#define NGRAPH 64
#define EPC 2048       // edges per chunk (hist/binA blocks)
#define MAXB 512       // max coarse buckets (n <= 131072)
#define NXC 8          // XCD classes (blockIdx&7 heuristic)
#define NREP 8         // pool replicas (atomic-contention spreading)
#define NPS 4          // nodes per slot in k_gz

__device__ inline unsigned short f2bf(float f) {
    unsigned u = __float_as_uint(f);
    u += 0x7FFF + ((u >> 16) & 1);          // RNE
    return (unsigned short)(u >> 16);
}
__device__ inline unsigned packbf(float lo, float hi) {
    return (unsigned)f2bf(lo) | ((unsigned)f2bf(hi) << 16);
}
__device__ inline float bf2f(unsigned short u) {
    return __uint_as_float(((unsigned)u) << 16);
}

// ---------------- init: pool/pcnt/bcnt8 zero, C = W2@Wlin, bb2 = b2@Wlin -------
__global__ void k_init0(float* __restrict__ pool, float* __restrict__ pcnt,
                        const float* __restrict__ W2, const float* __restrict__ Wlin,
                        const float* __restrict__ b2, float* __restrict__ C,
                        float* __restrict__ bb2, int* __restrict__ bcnt8) {
    int i = blockIdx.x * 256 + threadIdx.x;
    if (i < MAXB * NXC) bcnt8[i] = 0;
    if (i < NREP * NGRAPH * NEXP) pool[i] = 0.0f;
    if (i < NREP * NGRAPH) pcnt[i] = 0.0f;
    int ci = i - NREP * NGRAPH * NEXP;
    if (ci >= 0 && ci < HID * NEXP) {        // C[k][j] = sum_m W2[k][m]*Wlin[m][j]
        int k = ci >> 3, j = ci & 7;
        float s = 0.0f;
        for (int m = 0; m < HID; m++) s += W2[k * HID + m] * Wlin[m * NEXP + j];
        C[ci] = s;
    }
    int bi = ci - HID * NEXP;
    if (bi >= 0 && bi < NEXP) {              // bb2[j] = sum_m b2[m]*Wlin[m][j]
        float s = 0.0f;
        for (int m = 0; m < HID; m++) s += b2[m] * Wlin[m * NEXP + bi];
        bb2[bi] = s;
    }
}

// ---------------- pass 0: per-(bucket, xcd-class) totals -----------------------
__global__ void k_hist(const int* __restrict__ dst, int* __restrict__ bcnt8,
                       int e, int nbuck) {
    __shared__ int h[MAXB];
    int c = blockIdx.x, t = threadIdx.x;
    int x = c & (NXC - 1);
    for (int b = t; b < nbuck; b += 256) h[b] = 0;
    __syncthreads();
    int start = c * EPC;
    int end = start + EPC < e ? start + EPC : e;
    for (int i = start + t; i < end; i += 256)
        atomicAdd(&h[dst[i] >> 8], 1);
    __syncthreads();
    for (int b = t; b < nbuck; b += 256)
        if (h[b]) atomicAdd(&bcnt8[b * NXC + x], h[b]);
}

// ---------------- scan of 8*nbuck entries + cursor init (1 block, 512 thr) -----
__global__ void k_cscan(const int* __restrict__ bcnt8, int* __restrict__ boff8,
                        int* __restrict__ gcur8, int e, int m /* = 8*nbuck */) {
    __shared__ int s[512];
    int t = threadIdx.x;
    int base = t * 8;
    int v[8];
    int sum = 0;
#pragma unroll
    for (int j = 0; j < 8; j++) {
        v[j] = (base + j < m) ? bcnt8[base + j] : 0;
        sum += v[j];
    }
    s[t] = sum;
    __syncthreads();
    for (int d = 1; d < 512; d <<= 1) {
        int x = (t >= d) ? s[t - d] : 0;
        __syncthreads();
        s[t] += x;
        __syncthreads();
    }
    int run = s[t] - sum;               // exclusive
#pragma unroll
    for (int j = 0; j < 8; j++) {
        if (base + j < m) {
            boff8[base + j] = run;
            gcur8[base + j] = run;
        }
        run += v[j];
    }
    if (t == 0) boff8[m] = e;
}

// ---------------- pass A: LDS counting-sort binning, coalesced run writes ------
__global__ void __launch_bounds__(256) k_binA(
        const int* __restrict__ src, const int* __restrict__ dst,
        int* __restrict__ gcur8, unsigned* __restrict__ binned, int e, int nbuck) {
    __shared__ int h[MAXB];
    __shared__ int ssum[256];
    __shared__ int lstart[MAXB];
    __shared__ int lcur[MAXB];
    __shared__ int gbase[MAXB];
    __shared__ unsigned packed[EPC];
    __shared__ unsigned short sbkt[EPC];
    int c = blockIdx.x, t = threadIdx.x;
    int x = c & (NXC - 1);
    int start = c * EPC;
    int m = e - start < EPC ? e - start : EPC;

    int d[8], sv[8];
#pragma unroll
    for (int j = 0; j < 8; j++) {
        int idx = j * 256 + t;
        if (idx < m) { d[j] = dst[start + idx]; sv[j] = src[start + idx]; }
    }
    h[t] = 0; h[t + 256] = 0;
    __syncthreads();
#pragma unroll
    for (int j = 0; j < 8; j++)
        if (j * 256 + t < m) atomicAdd(&h[d[j] >> 8], 1);
    __syncthreads();
    // exclusive scan of 512 counters (2 per thread)
    int v0 = h[2 * t], v1 = h[2 * t + 1];
    int sum = v0 + v1;
    ssum[t] = sum;
    __syncthreads();
    for (int dd = 1; dd < 256; dd <<= 1) {
        int xx = (t >= dd) ? ssum[t - dd] : 0;
        __syncthreads();
        ssum[t] += xx;
        __syncthreads();
    }
    int ex = ssum[t] - sum;
    lstart[2 * t] = ex;     lstart[2 * t + 1] = ex + v0;
    lcur[2 * t]   = ex;     lcur[2 * t + 1]   = ex + v0;
    __syncthreads();
    // global range reservation per touched bucket
    for (int b = t; b < nbuck; b += 256)
        gbase[b] = h[b] ? atomicAdd(&gcur8[b * NXC + x], h[b]) : 0;
    // LDS sort (scatter to dense local ranks)
#pragma unroll
    for (int j = 0; j < 8; j++) {
        if (j * 256 + t < m) {
            int b = d[j] >> 8;
            int p = atomicAdd(&lcur[b], 1);
            packed[p] = ((unsigned)(d[j] & 255) << 24) | (unsigned)sv[j];
            sbkt[p] = (unsigned short)b;
        }
    }
    __syncthreads();
    // coalesced write-out: consecutive local ranks -> consecutive global slots
    for (int idx = t; idx < m; idx += 256) {
        int b = sbkt[idx];
        binned[gbase[b] + (idx - lstart[b])] = packed[idx];
    }
}

// ---------------- pass B: per-bucket fine sort + cnt/off/dinv + xs -------------
__global__ void k_binB(const unsigned* __restrict__ binned, const int* __restrict__ boff8,
                       const float* __restrict__ an, const float* __restrict__ pos,
                       int* __restrict__ cnt, int* __restrict__ off,
                       float* __restrict__ dinv, float4* __restrict__ xs,
                       int* __restrict__ eidx, int n) {
    __shared__ int h[256];
    __shared__ int sc[256];
    __shared__ int cur[256];
    int b = blockIdx.x, t = threadIdx.x;
    int s0 = boff8[b * NXC], s1 = boff8[(b + 1) * NXC];
    h[t] = 0;
    __syncthreads();
    for (int k = s0 + t; k < s1; k += 256)
        atomicAdd(&h[binned[k] >> 24], 1);
    __syncthreads();
    int v = h[t];
    sc[t] = v;
    __syncthreads();
    for (int d = 1; d < 256; d <<= 1) {
        int x = (t >= d) ? sc[t - d] : 0;
        __syncthreads();
        sc[t] += x;
        __syncthreads();
    }
    int ex = sc[t] - v;          // exclusive within bucket
    cur[t] = ex;
    int node = (b << 8) + t;
    if (node < n) {
        float di = rsqrtf((float)v + 1.0f);   // +1 = self-loop
        cnt[node]  = v;
        off[node]  = s0 + ex;
        dinv[node] = di;
        xs[node] = make_float4(an[node] * di, pos[3 * node] * di,
                               pos[3 * node + 1] * di, pos[3 * node + 2] * di);
    }
    __syncthreads();
    for (int k = s0 + t; k < s1; k += 256) {
        unsigned u = binned[k];
        int p = atomicAdd(&cur[u >> 24], 1);
        eidx[s0 + p] = (int)(u & 0xFFFFFF);
    }
}

// ---------------- fused layer-1 gather + dense + z projection ------------------
// one thread per node: register gather of agg4, then k-loop with wave-uniform
// weight reads (compiler emits scalar loads), z = (relu(dinv*agg4@W1+b1)@C)*dinv
__global__ void k_gxz(const float4* __restrict__ xs, const int* __restrict__ eidx,
                      const int* __restrict__ off, const int* __restrict__ cnt,
                      const float* __restrict__ dinv, const float* __restrict__ W1,
                      const float* __restrict__ b1, const float* __restrict__ C,
                      uint4* __restrict__ z, int n) {
    int i = blockIdx.x * 256 + threadIdx.x;
    if (i >= n) return;
    float4 a = xs[i];                       // self-loop
    int o = off[i], c = cnt[i];
    int k = 0;
    for (; k + 8 <= c; k += 8) {
        int id[8];
#pragma unroll
        for (int j = 0; j < 8; j++) id[j] = eidx[o + k + j];
        float4 vv[8];
#pragma unroll
        for (int j = 0; j < 8; j++) vv[j] = xs[id[j]];
#pragma unroll
        for (int j = 0; j < 8; j++) {
            a.x += vv[j].x; a.y += vv[j].y; a.z += vv[j].z; a.w += vv[j].w;
        }
    }
    for (; k < c; k++) {
        float4 vv = xs[eidx[o + k]];
        a.x += vv.x; a.y += vv.y; a.z += vv.z; a.w += vv.w;
    }
    float di = dinv[i];
    float z0 = 0.f, z1 = 0.f, z2 = 0.f, z3 = 0.f,
          z4 = 0.f, z5 = 0.f, z6 = 0.f, z7 = 0.f;
#pragma unroll 4
    for (int kk = 0; kk < HID; kk++) {      // all weight indices wave-uniform
        float x1k = fmaxf(di * (a.x * W1[kk] + a.y * W1[HID + kk] +
                                a.z * W1[2 * HID + kk] + a.w * W1[3 * HID + kk])
                          + b1[kk], 0.0f);
        const float* cr = C + kk * NEXP;
        z0 += x1k * cr[0]; z1 += x1k * cr[1];
        z2 += x1k * cr[2]; z3 += x1k * cr[3];
        z4 += x1k * cr[4]; z5 += x1k * cr[5];
        z6 += x1k * cr[6]; z7 += x1k * cr[7];
    }
    uint4 outv;
    outv.x = packbf(z0 * di, z1 * di);
    outv.y = packbf(z2 * di, z3 * di);
    outv.z = packbf(z4 * di, z5 * di);
    outv.w = packbf(z6 * di, z7 * di);
    z[i] = outv;
}

// ---------------- fused gather2 (8-dim bf16 z) + segment pooling ---------------
__global__ void k_gz(const unsigned short* __restrict__ z, const int* __restrict__ eidx,
                     const int* __restrict__ off, const int* __restrict__ cnt,
                     const float* __restrict__ dinv, const int* __restrict__ batch,
                     float* __restrict__ pool, float* __restrict__ pcnt, int n) {
    int t = threadIdx.x;
    int slot = t >> 3;          // 0..31 within block
    int j = t & 7;
    int i0 = blockIdx.x * (32 * NPS) + slot * NPS;
    if (i0 >= n) return;
    int i1 = i0 + NPS < n ? i0 + NPS : n;
    int rep = (blockIdx.x + slot) & (NREP - 1);
    float* rp  = pool + (size_t)rep * NGRAPH * NEXP;
    float* rpc = pcnt + (size_t)rep * NGRAPH;

    int curg = -1;
    float r = 0.0f, runlen = 0.0f;
    for (int i = i0; i < i1; i++) {
        float acc = bf2f(z[(size_t)i * NEXP + j]);   // self-loop
        int o = off[i], c = cnt[i];
        int k = 0;
        for (; k + 4 <= c; k += 4) {
            int s0 = eidx[o + k], s1 = eidx[o + k + 1];
            int s2 = eidx[o + k + 2], s3 = eidx[o + k + 3];
            unsigned short u0 = z[(size_t)s0 * NEXP + j];
            unsigned short u1 = z[(size_t)s1 * NEXP + j];
            unsigned short u2 = z[(size_t)s2 * NEXP + j];
            unsigned short u3 = z[(size_t)s3 * NEXP + j];
            acc += bf2f(u0) + bf2f(u1) + bf2f(u2) + bf2f(u3);
        }
        for (; k < c; k++)
            acc += bf2f(z[(size_t)eidx[o + k] * NEXP + j]);
        float v = dinv[i] * acc;
        int g = batch[i];
        if (g != curg) {                     // slot-uniform branch
            if (curg >= 0) {
                atomicAdd(&rp[curg * NEXP + j], r);
                if (j == 0) atomicAdd(&rpc[curg], runlen);
            }
            curg = g; r = v; runlen = 1.0f;
        } else { r += v; runlen += 1.0f; }
    }
    if (curg >= 0) {
        atomicAdd(&rp[curg * NEXP + j], r);
        if (j == 0) atomicAdd(&rpc[curg], runlen);
    }
}

// ---------------- replica-sum + mean + (blin + b2@Wlin) + log_softmax ----------
__global__ void k_lsm(const float* __restrict__ pool, const float* __restrict__ pcnt,
                      const float* __restrict__ blin, const float* __restrict__ bb2,
                      float* __restrict__ out) {
    int g = threadIdx.x;
    if (g >= NGRAPH) return;
    float p[NEXP];
#pragma unroll
    for (int k = 0; k < NEXP; k++) p[k] = 0.0f;
    float cg = 0.0f;
#pragma unroll
    for (int rr = 0; rr < NREP; rr++) {
#pragma unroll
        for (int k = 0; k < NEXP; k++) p[k] += pool[rr * NGRAPH * NEXP + g * NEXP + k];
        cg += pcnt[rr * NGRAPH + g];
    }
    float inv = 1.0f / fmaxf(cg, 1.0f);
    float v[NEXP], m = -1e30f;
#pragma unroll
    for (int k = 0; k < NEXP; k++) {
        v[k] = p[k] * inv + blin[k] + bb2[k];
        m = fmaxf(m, v[k]);
    }
    float s = 0.0f;
#pragma unroll
    for (int k = 0; k < NEXP; k++) s += expf(v[k] - m);
    float ls = logf(s);
#pragma unroll
    for (int k = 0; k < NEXP; k++) out[g * NEXP + k] = v[k] - m - ls;
}

extern "C" void kernel_launch(void* const* d_in, const int* in_sizes, int n_in,
                              void* d_out, int out_size, void* d_ws, size_t ws_size,
                              hipStream_t stream) {
    const float* an   = (const float*)d_in[0];
    const float* pos  = (const float*)d_in[1];
    const int*   ei   = (const int*)d_in[2];     // [2, E] flat (int32 view)
    const int*   batch= (const int*)d_in[3];
    const float* W1   = (const float*)d_in[4];
    const float* b1   = (const float*)d_in[5];
    const float* W2   = (const float*)d_in[6];
    const float* b2   = (const float*)d_in[7];
    const float* Wlin = (const float*)d_in[8];
    const float* blin = (const float*)d_in[9];
    float* out = (float*)d_out;

    const int n = in_sizes[0];
    const int e = in_sizes[2] / 2;
    const int* src = ei;
    const int* dst = ei + e;

    const int nbuck = (n + 255) >> 8;            // coarse buckets (<= MAXB)
    const int ch    = (e + EPC - 1) / EPC;       // chunks

    // workspace layout (16B-aligned buffers first)
    char* p = (char*)d_ws;
    float4* xs    = (float4*)p;       p += sizeof(float4) * (size_t)n;
    uint4*  z     = (uint4*)p;        p += sizeof(uint4) * (size_t)n;   // bf16[8]/node
    float* C      = (float*)p;        p += sizeof(float) * HID * NEXP;
    float* bb2    = (float*)p;        p += sizeof(float) * NEXP;
    float* dinv   = (float*)p;        p += sizeof(float) * (size_t)n;
    float* pool   = (float*)p;        p += sizeof(float) * NREP * NGRAPH * NEXP;
    float* pcnt   = (float*)p;        p += sizeof(float) * NREP * NGRAPH;
    int*   cnt    = (int*)p;          p += sizeof(int) * (size_t)n;
    int*   off    = (int*)p;          p += sizeof(int) * (size_t)n;
    int*   bcnt8  = (int*)p;          p += sizeof(int) * (MAXB * NXC + 8);
    int*   boff8  = (int*)p;          p += sizeof(int) * (MAXB * NXC + 8);
    int*   gcur8  = (int*)p;          p += sizeof(int) * (MAXB * NXC + 8);
    unsigned* binned = (unsigned*)p;  p += sizeof(unsigned) * (size_t)e;
    int*   eidx   = (int*)p;          p += sizeof(int) * (size_t)e;

    // init + CSR build via dynamic-reservation counting sort (LDS-sorted writes)
    const int initN = NREP * NGRAPH * NEXP + HID * NEXP + NEXP;
    const int initG = initN > MAXB * NXC ? initN : MAXB * NXC;
    k_init0<<<(initG + 255) / 256, 256, 0, stream>>>(pool, pcnt, W2, Wlin, b2, C, bb2, bcnt8);
    k_hist<<<ch, 256, 0, stream>>>(dst, bcnt8, e, nbuck);
    k_cscan<<<1, 512, 0, stream>>>(bcnt8, boff8, gcur8, e, NXC * nbuck);
    k_binA<<<ch, 256, 0, stream>>>(src, dst, gcur8, binned, e, nbuck);
    k_binB<<<nbuck, 256, 0, stream>>>(binned, boff8, an, pos, cnt, off, dinv, xs, eidx, n);

    // fused layer-1 gather + dense + projection to z (8-dim)
    k_gxz<<<(n + 255) / 256, 256, 0, stream>>>(xs, eidx, off, cnt, dinv, W1, b1, C, z, n);

    // layer 2 gather in 8-dim z-space + pooling, then log_softmax
    k_gz<<<(n + 32 * NPS - 1) / (32 * NPS), 256, 0, stream>>>((const unsigned short*)z,
                                                              eidx, off, cnt, dinv,
                                                              batch, pool, pcnt, n);
    k_lsm<<<1, 64, 0, stream>>>(pool, pcnt, blin, bb2, out);
}